// Round 1
// baseline (3887.497 us; speedup 1.0000x reference)
//
#include <hip/hip_runtime.h>
#include <cstdint>
#include <cstddef>

#define D 128
#define DDEC 512

// ---------------------------------------------------------------- utils
__global__ void detect_i64(const int* __restrict__ ei, int* __restrict__ flag) {
  if (threadIdx.x == 0 && blockIdx.x == 0) {
    int allz = 1;
    for (int k = 0; k < 64; ++k)
      if (ei[2 * k + 1] != 0) { allz = 0; break; }
    *flag = allz ? 2 : 1;  // 2 => int64 storage read as int32 pairs
  }
}

// 32 threads per edge, float4 per thread
__global__ __launch_bounds__(256) void scatter_kernel(
    const int* __restrict__ ei, const float* __restrict__ x,
    float* __restrict__ msg, float* __restrict__ cnt,
    const int* __restrict__ flag, int E)
{
  long long t = (long long)blockIdx.x * 256 + threadIdx.x;
  long long e = t >> 5;
  int j = (int)(t & 31);
  if (e >= E) return;
  int s = *flag;
  int src = ei[e * s];
  int dst = ei[((long long)E + e) * s];
  float4 v = *(const float4*)&x[(size_t)src * D + j * 4];
  float* m = &msg[(size_t)dst * D + j * 4];
  atomicAdd(m + 0, v.x);
  atomicAdd(m + 1, v.y);
  atomicAdd(m + 2, v.z);
  atomicAdd(m + 3, v.w);
  if (j == 0) atomicAdd(&cnt[dst], 1.0f);
}

__global__ __launch_bounds__(256) void aggr_kernel(
    float* __restrict__ msg, const float* __restrict__ cnt, int N)
{
  long long t = (long long)blockIdx.x * 256 + threadIdx.x;
  if (t >= (long long)N * 32) return;
  int node = (int)(t >> 5);
  int j = (int)(t & 31);
  float c = cnt[node];
  if (c < 1.0f) c = 1.0f;
  float inv = 1.0f / c;
  float4* p = (float4*)&msg[(size_t)node * D + j * 4];
  float4 v = *p;
  v.x *= inv; v.y *= inv; v.z *= inv; v.w *= inv;
  *p = v;
}

// ------------------------------------------------- h = leaky(aggr@Wl^T + bl + x@Wr^T, 0.5)
__global__ __launch_bounds__(256) void gemm_h_kernel(
    const float* __restrict__ A1, const float* __restrict__ A2,
    const float* __restrict__ W1, const float* __restrict__ W2,
    const float* __restrict__ bias, float* __restrict__ C, int N)
{
  __shared__ __align__(16) float As1[16][64], As2[16][64], Ws1[16][64], Ws2[16][64];
  const int t = threadIdx.x;
  const int row0 = blockIdx.x * 64;
  const int col0 = blockIdx.y * 64;
  const int lr = t >> 2, lk = (t & 3) << 2;
  const int ty = t >> 4, tx = t & 15;
  float acc[4][4] = {};
  const int arow = row0 + lr;
  const bool av = arow < N;
  for (int k0 = 0; k0 < D; k0 += 16) {
    float4 a1 = make_float4(0, 0, 0, 0), a2 = make_float4(0, 0, 0, 0);
    if (av) {
      a1 = *(const float4*)&A1[(size_t)arow * D + k0 + lk];
      a2 = *(const float4*)&A2[(size_t)arow * D + k0 + lk];
    }
    float4 w1 = *(const float4*)&W1[(size_t)(col0 + lr) * D + k0 + lk];
    float4 w2 = *(const float4*)&W2[(size_t)(col0 + lr) * D + k0 + lk];
    __syncthreads();
    As1[lk + 0][lr] = a1.x; As1[lk + 1][lr] = a1.y; As1[lk + 2][lr] = a1.z; As1[lk + 3][lr] = a1.w;
    As2[lk + 0][lr] = a2.x; As2[lk + 1][lr] = a2.y; As2[lk + 2][lr] = a2.z; As2[lk + 3][lr] = a2.w;
    Ws1[lk + 0][lr] = w1.x; Ws1[lk + 1][lr] = w1.y; Ws1[lk + 2][lr] = w1.z; Ws1[lk + 3][lr] = w1.w;
    Ws2[lk + 0][lr] = w2.x; Ws2[lk + 1][lr] = w2.y; Ws2[lk + 2][lr] = w2.z; Ws2[lk + 3][lr] = w2.w;
    __syncthreads();
#pragma unroll
    for (int kk = 0; kk < 16; ++kk) {
      float4 v;
      v = *(const float4*)&As1[kk][ty << 2]; const float fa1[4] = {v.x, v.y, v.z, v.w};
      v = *(const float4*)&As2[kk][ty << 2]; const float fa2[4] = {v.x, v.y, v.z, v.w};
      v = *(const float4*)&Ws1[kk][tx << 2]; const float fw1[4] = {v.x, v.y, v.z, v.w};
      v = *(const float4*)&Ws2[kk][tx << 2]; const float fw2[4] = {v.x, v.y, v.z, v.w};
#pragma unroll
      for (int i = 0; i < 4; ++i)
#pragma unroll
        for (int j = 0; j < 4; ++j)
          acc[i][j] += fa1[i] * fw1[j] + fa2[i] * fw2[j];
    }
  }
  float4 bv = *(const float4*)&bias[col0 + (tx << 2)];
  const float b[4] = {bv.x, bv.y, bv.z, bv.w};
#pragma unroll
  for (int i = 0; i < 4; ++i) {
    int row = row0 + (ty << 2) + i;
    if (row < N) {
      float4 r;
      float v0 = acc[i][0] + b[0]; r.x = (v0 >= 0.f) ? v0 : 0.5f * v0;
      float v1 = acc[i][1] + b[1]; r.y = (v1 >= 0.f) ? v1 : 0.5f * v1;
      float v2 = acc[i][2] + b[2]; r.z = (v2 >= 0.f) ? v2 : 0.5f * v2;
      float v3 = acc[i][3] + b[3]; r.w = (v3 >= 0.f) ? v3 : 0.5f * v3;
      *(float4*)&C[(size_t)row * D + col0 + (tx << 2)] = r;
    }
  }
}

// ------------------------------------------------- z = prelu(h@Wp^T + bp, a)
__global__ __launch_bounds__(256) void gemm_z_kernel(
    const float* __restrict__ A, const float* __restrict__ W,
    const float* __restrict__ bias, const float* __restrict__ ap,
    float* __restrict__ C, int N)
{
  __shared__ __align__(16) float As[16][64], Ws[16][64];
  const int t = threadIdx.x;
  const int row0 = blockIdx.x * 64;
  const int col0 = blockIdx.y * 64;
  const int lr = t >> 2, lk = (t & 3) << 2;
  const int ty = t >> 4, tx = t & 15;
  float acc[4][4] = {};
  const int arow = row0 + lr;
  const bool av = arow < N;
  for (int k0 = 0; k0 < D; k0 += 16) {
    float4 a = make_float4(0, 0, 0, 0);
    if (av) a = *(const float4*)&A[(size_t)arow * D + k0 + lk];
    float4 w = *(const float4*)&W[(size_t)(col0 + lr) * D + k0 + lk];
    __syncthreads();
    As[lk + 0][lr] = a.x; As[lk + 1][lr] = a.y; As[lk + 2][lr] = a.z; As[lk + 3][lr] = a.w;
    Ws[lk + 0][lr] = w.x; Ws[lk + 1][lr] = w.y; Ws[lk + 2][lr] = w.z; Ws[lk + 3][lr] = w.w;
    __syncthreads();
#pragma unroll
    for (int kk = 0; kk < 16; ++kk) {
      float4 v;
      v = *(const float4*)&As[kk][ty << 2]; const float fa[4] = {v.x, v.y, v.z, v.w};
      v = *(const float4*)&Ws[kk][tx << 2]; const float fw[4] = {v.x, v.y, v.z, v.w};
#pragma unroll
      for (int i = 0; i < 4; ++i)
#pragma unroll
        for (int j = 0; j < 4; ++j)
          acc[i][j] += fa[i] * fw[j];
    }
  }
  float alpha = *ap;
  float4 bv = *(const float4*)&bias[col0 + (tx << 2)];
  const float b[4] = {bv.x, bv.y, bv.z, bv.w};
#pragma unroll
  for (int i = 0; i < 4; ++i) {
    int row = row0 + (ty << 2) + i;
    if (row < N) {
      float4 r;
      float v0 = acc[i][0] + b[0]; r.x = (v0 >= 0.f) ? v0 : alpha * v0;
      float v1 = acc[i][1] + b[1]; r.y = (v1 >= 0.f) ? v1 : alpha * v1;
      float v2 = acc[i][2] + b[2]; r.z = (v2 >= 0.f) ? v2 : alpha * v2;
      float v3 = acc[i][3] + b[3]; r.w = (v3 >= 0.f) ? v3 : alpha * v3;
      *(float4*)&C[(size_t)row * D + col0 + (tx << 2)] = r;
    }
  }
}

// ------------------------------------------------- d-stats: column sums/sumsq of h@Wd1^T+bd1
__global__ __launch_bounds__(256) void gemm_dstat_kernel(
    const float* __restrict__ A, const float* __restrict__ W,
    const float* __restrict__ bias,
    float* __restrict__ sums, float* __restrict__ sumsq, int N)
{
  __shared__ __align__(16) float As[16][64], Ws[16][64];
  __shared__ float red[16][64];
  const int t = threadIdx.x;
  const int row0 = blockIdx.x * 64;
  const int col0 = blockIdx.y * 64;
  const int lr = t >> 2, lk = (t & 3) << 2;
  const int ty = t >> 4, tx = t & 15;
  float acc[4][4] = {};
  const int arow = row0 + lr;
  const bool av = arow < N;
  for (int k0 = 0; k0 < D; k0 += 16) {
    float4 a = make_float4(0, 0, 0, 0);
    if (av) a = *(const float4*)&A[(size_t)arow * D + k0 + lk];
    float4 w = *(const float4*)&W[(size_t)(col0 + lr) * D + k0 + lk];
    __syncthreads();
    As[lk + 0][lr] = a.x; As[lk + 1][lr] = a.y; As[lk + 2][lr] = a.z; As[lk + 3][lr] = a.w;
    Ws[lk + 0][lr] = w.x; Ws[lk + 1][lr] = w.y; Ws[lk + 2][lr] = w.z; Ws[lk + 3][lr] = w.w;
    __syncthreads();
#pragma unroll
    for (int kk = 0; kk < 16; ++kk) {
      float4 v;
      v = *(const float4*)&As[kk][ty << 2]; const float fa[4] = {v.x, v.y, v.z, v.w};
      v = *(const float4*)&Ws[kk][tx << 2]; const float fw[4] = {v.x, v.y, v.z, v.w};
#pragma unroll
      for (int i = 0; i < 4; ++i)
#pragma unroll
        for (int j = 0; j < 4; ++j)
          acc[i][j] += fa[i] * fw[j];
    }
  }
  float4 bv = *(const float4*)&bias[col0 + (tx << 2)];
  const float b[4] = {bv.x, bv.y, bv.z, bv.w};
  float lsum[4] = {0, 0, 0, 0}, lsq[4] = {0, 0, 0, 0};
#pragma unroll
  for (int i = 0; i < 4; ++i) {
    int row = row0 + (ty << 2) + i;
    if (row < N) {
#pragma unroll
      for (int j = 0; j < 4; ++j) {
        float v = acc[i][j] + b[j];
        lsum[j] += v;
        lsq[j] += v * v;
      }
    }
  }
  __syncthreads();
#pragma unroll
  for (int j = 0; j < 4; ++j) red[ty][(tx << 2) + j] = lsum[j];
  __syncthreads();
  if (t < 64) {
    float s = 0;
#pragma unroll
    for (int k = 0; k < 16; ++k) s += red[k][t];
    atomicAdd(&sums[col0 + t], s);
  }
  __syncthreads();
#pragma unroll
  for (int j = 0; j < 4; ++j) red[ty][(tx << 2) + j] = lsq[j];
  __syncthreads();
  if (t < 64) {
    float s = 0;
#pragma unroll
    for (int k = 0; k < 16; ++k) s += red[k][t];
    atomicAdd(&sumsq[col0 + t], s);
  }
}

__global__ void finalize_kernel(
    const float* __restrict__ sums, const float* __restrict__ sumsq,
    const float* __restrict__ gamma, const float* __restrict__ beta,
    float* __restrict__ scale, float* __restrict__ shift, int N)
{
  int c = blockIdx.x * blockDim.x + threadIdx.x;
  if (c < DDEC) {
    float inv_n = 1.0f / (float)N;
    float mu = sums[c] * inv_n;
    float var = sumsq[c] * inv_n - mu * mu;
    float sc = gamma[c] * rsqrtf(var + 1e-5f);
    scale[c] = sc;
    shift[c] = beta[c] - mu * sc;
  }
}

// ------------------------------------------------- rec: fused d-recompute -> BN -> leaky -> @Wd2^T
__global__ __launch_bounds__(256) void rec_kernel(
    const float* __restrict__ h, const float* __restrict__ Wd1,
    const float* __restrict__ bd1,
    const float* __restrict__ scale, const float* __restrict__ shift,
    const float* __restrict__ Wd2, const float* __restrict__ bd2,
    float* __restrict__ rec, int N)
{
  __shared__ __align__(16) float hs[D][64];    // [k][row] 32KB
  __shared__ __align__(16) float dn[64][64];   // [c][row] 16KB
  __shared__ __align__(16) float W1s[16][64];  // [k][c]   4KB
  __shared__ __align__(16) float W2s[16][128]; // [cc][col] 8KB
  const int t = threadIdx.x;
  const int row0 = blockIdx.x * 64;
  const int ty1 = t >> 4, tx1 = t & 15;   // phase A: 4x4 over 64x64
  const int tyB = t >> 5, txB = t & 31;   // phase B: 8x4 over 64x128
  const int lr = t >> 2, lk = (t & 3) << 2;

#pragma unroll
  for (int rep = 0; rep < 8; ++rep) {
    int u = t + rep * 256;
    int r = u >> 5;
    int kb = (u & 31) << 2;
    float4 v = make_float4(0, 0, 0, 0);
    int row = row0 + r;
    if (row < N) v = *(const float4*)&h[(size_t)row * D + kb];
    hs[kb + 0][r] = v.x; hs[kb + 1][r] = v.y; hs[kb + 2][r] = v.z; hs[kb + 3][r] = v.w;
  }
  __syncthreads();

  float acc[8][4] = {};
  for (int c0 = 0; c0 < DDEC; c0 += 64) {
    // ---- phase A: dtile[64 rows][64 c] = hs @ Wd1[c0:c0+64]^T
    float dacc[4][4] = {};
    for (int k0 = 0; k0 < D; k0 += 16) {
      float4 w = *(const float4*)&Wd1[(size_t)(c0 + lr) * D + k0 + lk];
      __syncthreads();
      W1s[lk + 0][lr] = w.x; W1s[lk + 1][lr] = w.y; W1s[lk + 2][lr] = w.z; W1s[lk + 3][lr] = w.w;
      __syncthreads();
#pragma unroll
      for (int kk = 0; kk < 16; ++kk) {
        float4 v;
        v = *(const float4*)&hs[k0 + kk][ty1 << 2]; const float fa[4] = {v.x, v.y, v.z, v.w};
        v = *(const float4*)&W1s[kk][tx1 << 2];     const float fw[4] = {v.x, v.y, v.z, v.w};
#pragma unroll
        for (int i = 0; i < 4; ++i)
#pragma unroll
          for (int j = 0; j < 4; ++j)
            dacc[i][j] += fa[i] * fw[j];
      }
    }
    // ---- normalize + leaky into dn (transposed: dn[c][row])
#pragma unroll
    for (int j = 0; j < 4; ++j) {
      int cg = c0 + (tx1 << 2) + j;
      float bb = bd1[cg], sc = scale[cg], sh = shift[cg];
#pragma unroll
      for (int i = 0; i < 4; ++i) {
        float v = dacc[i][j] + bb;
        v = v * sc + sh;
        v = (v >= 0.f) ? v : 0.01f * v;
        dn[(tx1 << 2) + j][(ty1 << 2) + i] = v;
      }
    }
    // ---- phase B: acc += dn^T @ Wd2[:, c0:c0+64]^T
    for (int cc0 = 0; cc0 < 64; cc0 += 16) {
      int colA = t >> 2, ccb = (t & 3) << 2;
      float4 wa = *(const float4*)&Wd2[(size_t)colA * DDEC + c0 + cc0 + ccb];
      float4 wb = *(const float4*)&Wd2[(size_t)(colA + 64) * DDEC + c0 + cc0 + ccb];
      __syncthreads();
      W2s[ccb + 0][colA] = wa.x; W2s[ccb + 1][colA] = wa.y; W2s[ccb + 2][colA] = wa.z; W2s[ccb + 3][colA] = wa.w;
      W2s[ccb + 0][colA + 64] = wb.x; W2s[ccb + 1][colA + 64] = wb.y; W2s[ccb + 2][colA + 64] = wb.z; W2s[ccb + 3][colA + 64] = wb.w;
      __syncthreads();
#pragma unroll
      for (int cc = 0; cc < 16; ++cc) {
        float4 v;
        v = *(const float4*)&dn[cc0 + cc][tyB << 3];       const float a0[4] = {v.x, v.y, v.z, v.w};
        v = *(const float4*)&dn[cc0 + cc][(tyB << 3) + 4]; const float a1[4] = {v.x, v.y, v.z, v.w};
        v = *(const float4*)&W2s[cc][txB << 2];            const float w2[4] = {v.x, v.y, v.z, v.w};
#pragma unroll
        for (int j = 0; j < 4; ++j) {
#pragma unroll
          for (int i = 0; i < 4; ++i) {
            acc[i][j] += a0[i] * w2[j];
            acc[4 + i][j] += a1[i] * w2[j];
          }
        }
      }
    }
  }
  float4 bv = *(const float4*)&bd2[txB << 2];
  const float b2[4] = {bv.x, bv.y, bv.z, bv.w};
#pragma unroll
  for (int i = 0; i < 8; ++i) {
    int row = row0 + (tyB << 3) + i;
    if (row < N) {
      float4 r;
      r.x = acc[i][0] + b2[0];
      r.y = acc[i][1] + b2[1];
      r.z = acc[i][2] + b2[2];
      r.w = acc[i][3] + b2[3];
      *(float4*)&rec[(size_t)row * D + (txB << 2)] = r;
    }
  }
}

// ---------------------------------------------------------------- launch
extern "C" void kernel_launch(void* const* d_in, const int* in_sizes, int n_in,
                              void* d_out, int out_size, void* d_ws, size_t ws_size,
                              hipStream_t stream)
{
  const float* x   = (const float*)d_in[0];
  const int*   ei  = (const int*)d_in[1];
  const float* Wl  = (const float*)d_in[2];
  const float* bl  = (const float*)d_in[3];
  const float* Wr  = (const float*)d_in[4];
  const float* Wp  = (const float*)d_in[5];
  const float* bp  = (const float*)d_in[6];
  const float* ap  = (const float*)d_in[7];
  const float* Wd1 = (const float*)d_in[8];
  const float* bd1 = (const float*)d_in[9];
  const float* gm  = (const float*)d_in[10];
  const float* bt  = (const float*)d_in[11];
  const float* Wd2 = (const float*)d_in[12];
  const float* bd2 = (const float*)d_in[13];

  const int N = in_sizes[0] / D;   // 100000
  const int E = in_sizes[1] / 2;   // 1600000

  float* h_out   = (float*)d_out;
  float* z_out   = h_out + (size_t)N * D;
  float* rec_out = z_out + (size_t)N * D;
  float* tgt_out = rec_out + (size_t)N * D;

  float* cnt   = (float*)d_ws;
  float* sums  = cnt + N;
  float* sumsq = sums + DDEC;
  float* scale = sumsq + DDEC;
  float* shift = scale + DDEC;
  int*   flag  = (int*)(shift + DDEC);

  float* msg = z_out;  // use z output slot as msg_sum scratch (z computed later)

  hipMemsetAsync(msg, 0, (size_t)N * D * sizeof(float), stream);
  hipMemsetAsync(cnt, 0, (size_t)(N + 2 * DDEC) * sizeof(float), stream);

  detect_i64<<<1, 64, 0, stream>>>(ei, flag);

  long long sc_threads = (long long)E * 32;
  int sc_blocks = (int)((sc_threads + 255) / 256);
  scatter_kernel<<<sc_blocks, 256, 0, stream>>>(ei, x, msg, cnt, flag, E);

  long long ag_threads = (long long)N * 32;
  aggr_kernel<<<(int)((ag_threads + 255) / 256), 256, 0, stream>>>(msg, cnt, N);

  int rb = (N + 63) / 64;
  gemm_h_kernel<<<dim3(rb, 2), 256, 0, stream>>>(msg, x, Wl, Wr, bl, h_out, N);

  gemm_dstat_kernel<<<dim3(rb, 8), 256, 0, stream>>>(h_out, Wd1, bd1, sums, sumsq, N);
  finalize_kernel<<<2, 256, 0, stream>>>(sums, sumsq, gm, bt, scale, shift, N);

  gemm_z_kernel<<<dim3(rb, 2), 256, 0, stream>>>(h_out, Wp, bp, ap, z_out, N);

  rec_kernel<<<rb, 256, 0, stream>>>(h_out, Wd1, bd1, scale, shift, Wd2, bd2, rec_out, N);

  hipMemcpyAsync(tgt_out, x, (size_t)N * D * sizeof(float), hipMemcpyDeviceToDevice, stream);
}

// Round 2
// 1334.744 us; speedup vs baseline: 2.9125x; 2.9125x over previous
//
#include <hip/hip_runtime.h>
#include <cstdint>
#include <cstddef>

#define D 128
#define DDEC 512

// ---------------------------------------------------------------- utils
__global__ void detect_i64(const int* __restrict__ ei, int* __restrict__ flag) {
  if (threadIdx.x == 0 && blockIdx.x == 0) {
    int allz = 1;
    for (int k = 0; k < 64; ++k)
      if (ei[2 * k + 1] != 0) { allz = 0; break; }
    *flag = allz ? 2 : 1;  // 2 => int64 storage read as int32 pairs
  }
}

// ---------------------------------------------------------------- CSR build
__global__ __launch_bounds__(256) void count_deg(
    const int* __restrict__ ei, int* __restrict__ deg,
    const int* __restrict__ flag, int E)
{
  int e = blockIdx.x * 256 + threadIdx.x;
  if (e >= E) return;
  int s = *flag;
  int dst = ei[((long long)E + e) * s];
  atomicAdd(&deg[dst], 1);
}

__global__ __launch_bounds__(256) void scan_reduce(
    const int* __restrict__ deg, int* __restrict__ bsum, int N)
{
  __shared__ int red[256];
  int base = blockIdx.x * 1024 + threadIdx.x * 4;
  int s = 0;
#pragma unroll
  for (int k = 0; k < 4; ++k) { int i = base + k; if (i < N) s += deg[i]; }
  red[threadIdx.x] = s;
  __syncthreads();
  for (int off = 128; off > 0; off >>= 1) {
    if (threadIdx.x < off) red[threadIdx.x] += red[threadIdx.x + off];
    __syncthreads();
  }
  if (threadIdx.x == 0) bsum[blockIdx.x] = red[0];
}

__global__ void scan_bsum(int* __restrict__ bsum, int* __restrict__ rowptr,
                          int NB, int N, int E)
{
  __shared__ int tmp[256];
  int t = threadIdx.x;
  int v = (t < NB) ? bsum[t] : 0;
  tmp[t] = v;
  __syncthreads();
  for (int off = 1; off < 256; off <<= 1) {
    int add = (t >= off) ? tmp[t - off] : 0;
    __syncthreads();
    tmp[t] += add;
    __syncthreads();
  }
  if (t < NB) bsum[t] = tmp[t] - v;  // exclusive
  if (t == 0) rowptr[N] = E;
}

__global__ __launch_bounds__(256) void scan_final(
    const int* __restrict__ deg, const int* __restrict__ bsum,
    int* __restrict__ rowptr, int N)
{
  __shared__ int tsum[256];
  int base = blockIdx.x * 1024 + threadIdx.x * 4;
  int loc[4]; int s = 0;
#pragma unroll
  for (int k = 0; k < 4; ++k) { int i = base + k; loc[k] = (i < N) ? deg[i] : 0; s += loc[k]; }
  tsum[threadIdx.x] = s;
  __syncthreads();
  for (int off = 1; off < 256; off <<= 1) {
    int add = (threadIdx.x >= off) ? tsum[threadIdx.x - off] : 0;
    __syncthreads();
    tsum[threadIdx.x] += add;
    __syncthreads();
  }
  int excl = tsum[threadIdx.x] - s + bsum[blockIdx.x];
#pragma unroll
  for (int k = 0; k < 4; ++k) {
    int i = base + k;
    if (i < N) { rowptr[i] = excl; excl += loc[k]; }
  }
}

__global__ __launch_bounds__(256) void fill_csr(
    const int* __restrict__ ei, const int* __restrict__ rowptr,
    int* __restrict__ fillc, int* __restrict__ colidx,
    const int* __restrict__ flag, int E)
{
  int e = blockIdx.x * 256 + threadIdx.x;
  if (e >= E) return;
  int s = *flag;
  int src = ei[(long long)e * s];
  int dst = ei[((long long)E + e) * s];
  int pos = rowptr[dst] + atomicAdd(&fillc[dst], 1);
  colidx[pos] = src;
}

// ---------------------------------------------------------------- gather-mean
// one wave per node; lane owns 2 consecutive columns
__global__ __launch_bounds__(256) void aggregate_kernel(
    const int* __restrict__ rowptr, const int* __restrict__ colidx,
    const float* __restrict__ x, float* __restrict__ aggr, int N)
{
  int wave = (blockIdx.x * 256 + threadIdx.x) >> 6;
  int lane = threadIdx.x & 63;
  if (wave >= N) return;
  int s = rowptr[wave], epos = rowptr[wave + 1];
  float2 acc = make_float2(0.f, 0.f);
  int e = s;
  for (; e + 1 < epos; e += 2) {
    int s0 = colidx[e], s1 = colidx[e + 1];
    const float2 v0 = *(const float2*)&x[(size_t)s0 * D + lane * 2];
    const float2 v1 = *(const float2*)&x[(size_t)s1 * D + lane * 2];
    acc.x += v0.x + v1.x;
    acc.y += v0.y + v1.y;
  }
  if (e < epos) {
    int s0 = colidx[e];
    const float2 v0 = *(const float2*)&x[(size_t)s0 * D + lane * 2];
    acc.x += v0.x;
    acc.y += v0.y;
  }
  int degn = epos - s;
  float inv = 1.0f / (float)(degn > 0 ? degn : 1);
  acc.x *= inv; acc.y *= inv;
  *(float2*)&aggr[(size_t)wave * D + lane * 2] = acc;
}

// ------------------------------------------------- h = leaky(aggr@Wl^T + bl + x@Wr^T, 0.5)
__global__ __launch_bounds__(256) void gemm_h_kernel(
    const float* __restrict__ A1, const float* __restrict__ A2,
    const float* __restrict__ W1, const float* __restrict__ W2,
    const float* __restrict__ bias, float* __restrict__ C, int N)
{
  __shared__ __align__(16) float As1[16][64], As2[16][64], Ws1[16][64], Ws2[16][64];
  const int t = threadIdx.x;
  const int row0 = blockIdx.x * 64;
  const int col0 = blockIdx.y * 64;
  const int lr = t >> 2, lk = (t & 3) << 2;
  const int ty = t >> 4, tx = t & 15;
  float acc[4][4] = {};
  const int arow = row0 + lr;
  const bool av = arow < N;
  for (int k0 = 0; k0 < D; k0 += 16) {
    float4 a1 = make_float4(0, 0, 0, 0), a2 = make_float4(0, 0, 0, 0);
    if (av) {
      a1 = *(const float4*)&A1[(size_t)arow * D + k0 + lk];
      a2 = *(const float4*)&A2[(size_t)arow * D + k0 + lk];
    }
    float4 w1 = *(const float4*)&W1[(size_t)(col0 + lr) * D + k0 + lk];
    float4 w2 = *(const float4*)&W2[(size_t)(col0 + lr) * D + k0 + lk];
    __syncthreads();
    As1[lk + 0][lr] = a1.x; As1[lk + 1][lr] = a1.y; As1[lk + 2][lr] = a1.z; As1[lk + 3][lr] = a1.w;
    As2[lk + 0][lr] = a2.x; As2[lk + 1][lr] = a2.y; As2[lk + 2][lr] = a2.z; As2[lk + 3][lr] = a2.w;
    Ws1[lk + 0][lr] = w1.x; Ws1[lk + 1][lr] = w1.y; Ws1[lk + 2][lr] = w1.z; Ws1[lk + 3][lr] = w1.w;
    Ws2[lk + 0][lr] = w2.x; Ws2[lk + 1][lr] = w2.y; Ws2[lk + 2][lr] = w2.z; Ws2[lk + 3][lr] = w2.w;
    __syncthreads();
#pragma unroll
    for (int kk = 0; kk < 16; ++kk) {
      float4 v;
      v = *(const float4*)&As1[kk][ty << 2]; const float fa1[4] = {v.x, v.y, v.z, v.w};
      v = *(const float4*)&As2[kk][ty << 2]; const float fa2[4] = {v.x, v.y, v.z, v.w};
      v = *(const float4*)&Ws1[kk][tx << 2]; const float fw1[4] = {v.x, v.y, v.z, v.w};
      v = *(const float4*)&Ws2[kk][tx << 2]; const float fw2[4] = {v.x, v.y, v.z, v.w};
#pragma unroll
      for (int i = 0; i < 4; ++i)
#pragma unroll
        for (int j = 0; j < 4; ++j)
          acc[i][j] += fa1[i] * fw1[j] + fa2[i] * fw2[j];
    }
  }
  float4 bv = *(const float4*)&bias[col0 + (tx << 2)];
  const float b[4] = {bv.x, bv.y, bv.z, bv.w};
#pragma unroll
  for (int i = 0; i < 4; ++i) {
    int row = row0 + (ty << 2) + i;
    if (row < N) {
      float4 r;
      float v0 = acc[i][0] + b[0]; r.x = (v0 >= 0.f) ? v0 : 0.5f * v0;
      float v1 = acc[i][1] + b[1]; r.y = (v1 >= 0.f) ? v1 : 0.5f * v1;
      float v2 = acc[i][2] + b[2]; r.z = (v2 >= 0.f) ? v2 : 0.5f * v2;
      float v3 = acc[i][3] + b[3]; r.w = (v3 >= 0.f) ? v3 : 0.5f * v3;
      *(float4*)&C[(size_t)row * D + col0 + (tx << 2)] = r;
    }
  }
}

// ------------------------------------------------- z = prelu(h@Wp^T + bp, a)
__global__ __launch_bounds__(256) void gemm_z_kernel(
    const float* __restrict__ A, const float* __restrict__ W,
    const float* __restrict__ bias, const float* __restrict__ ap,
    float* __restrict__ C, int N)
{
  __shared__ __align__(16) float As[16][64], Ws[16][64];
  const int t = threadIdx.x;
  const int row0 = blockIdx.x * 64;
  const int col0 = blockIdx.y * 64;
  const int lr = t >> 2, lk = (t & 3) << 2;
  const int ty = t >> 4, tx = t & 15;
  float acc[4][4] = {};
  const int arow = row0 + lr;
  const bool av = arow < N;
  for (int k0 = 0; k0 < D; k0 += 16) {
    float4 a = make_float4(0, 0, 0, 0);
    if (av) a = *(const float4*)&A[(size_t)arow * D + k0 + lk];
    float4 w = *(const float4*)&W[(size_t)(col0 + lr) * D + k0 + lk];
    __syncthreads();
    As[lk + 0][lr] = a.x; As[lk + 1][lr] = a.y; As[lk + 2][lr] = a.z; As[lk + 3][lr] = a.w;
    Ws[lk + 0][lr] = w.x; Ws[lk + 1][lr] = w.y; Ws[lk + 2][lr] = w.z; Ws[lk + 3][lr] = w.w;
    __syncthreads();
#pragma unroll
    for (int kk = 0; kk < 16; ++kk) {
      float4 v;
      v = *(const float4*)&As[kk][ty << 2]; const float fa[4] = {v.x, v.y, v.z, v.w};
      v = *(const float4*)&Ws[kk][tx << 2]; const float fw[4] = {v.x, v.y, v.z, v.w};
#pragma unroll
      for (int i = 0; i < 4; ++i)
#pragma unroll
        for (int j = 0; j < 4; ++j)
          acc[i][j] += fa[i] * fw[j];
    }
  }
  float alpha = *ap;
  float4 bv = *(const float4*)&bias[col0 + (tx << 2)];
  const float b[4] = {bv.x, bv.y, bv.z, bv.w};
#pragma unroll
  for (int i = 0; i < 4; ++i) {
    int row = row0 + (ty << 2) + i;
    if (row < N) {
      float4 r;
      float v0 = acc[i][0] + b[0]; r.x = (v0 >= 0.f) ? v0 : alpha * v0;
      float v1 = acc[i][1] + b[1]; r.y = (v1 >= 0.f) ? v1 : alpha * v1;
      float v2 = acc[i][2] + b[2]; r.z = (v2 >= 0.f) ? v2 : alpha * v2;
      float v3 = acc[i][3] + b[3]; r.w = (v3 >= 0.f) ? v3 : alpha * v3;
      *(float4*)&C[(size_t)row * D + col0 + (tx << 2)] = r;
    }
  }
}

// ------------------------------------------------- d-stats: column sums/sumsq of h@Wd1^T+bd1
__global__ __launch_bounds__(256) void gemm_dstat_kernel(
    const float* __restrict__ A, const float* __restrict__ W,
    const float* __restrict__ bias,
    float* __restrict__ sums, float* __restrict__ sumsq, int N)
{
  __shared__ __align__(16) float As[16][64], Ws[16][64];
  __shared__ float red[16][64];
  const int t = threadIdx.x;
  const int row0 = blockIdx.x * 64;
  const int col0 = blockIdx.y * 64;
  const int lr = t >> 2, lk = (t & 3) << 2;
  const int ty = t >> 4, tx = t & 15;
  float acc[4][4] = {};
  const int arow = row0 + lr;
  const bool av = arow < N;
  for (int k0 = 0; k0 < D; k0 += 16) {
    float4 a = make_float4(0, 0, 0, 0);
    if (av) a = *(const float4*)&A[(size_t)arow * D + k0 + lk];
    float4 w = *(const float4*)&W[(size_t)(col0 + lr) * D + k0 + lk];
    __syncthreads();
    As[lk + 0][lr] = a.x; As[lk + 1][lr] = a.y; As[lk + 2][lr] = a.z; As[lk + 3][lr] = a.w;
    Ws[lk + 0][lr] = w.x; Ws[lk + 1][lr] = w.y; Ws[lk + 2][lr] = w.z; Ws[lk + 3][lr] = w.w;
    __syncthreads();
#pragma unroll
    for (int kk = 0; kk < 16; ++kk) {
      float4 v;
      v = *(const float4*)&As[kk][ty << 2]; const float fa[4] = {v.x, v.y, v.z, v.w};
      v = *(const float4*)&Ws[kk][tx << 2]; const float fw[4] = {v.x, v.y, v.z, v.w};
#pragma unroll
      for (int i = 0; i < 4; ++i)
#pragma unroll
        for (int j = 0; j < 4; ++j)
          acc[i][j] += fa[i] * fw[j];
    }
  }
  float4 bv = *(const float4*)&bias[col0 + (tx << 2)];
  const float b[4] = {bv.x, bv.y, bv.z, bv.w};
  float lsum[4] = {0, 0, 0, 0}, lsq[4] = {0, 0, 0, 0};
#pragma unroll
  for (int i = 0; i < 4; ++i) {
    int row = row0 + (ty << 2) + i;
    if (row < N) {
#pragma unroll
      for (int j = 0; j < 4; ++j) {
        float v = acc[i][j] + b[j];
        lsum[j] += v;
        lsq[j] += v * v;
      }
    }
  }
  __syncthreads();
#pragma unroll
  for (int j = 0; j < 4; ++j) red[ty][(tx << 2) + j] = lsum[j];
  __syncthreads();
  if (t < 64) {
    float s = 0;
#pragma unroll
    for (int k = 0; k < 16; ++k) s += red[k][t];
    atomicAdd(&sums[col0 + t], s);
  }
  __syncthreads();
#pragma unroll
  for (int j = 0; j < 4; ++j) red[ty][(tx << 2) + j] = lsq[j];
  __syncthreads();
  if (t < 64) {
    float s = 0;
#pragma unroll
    for (int k = 0; k < 16; ++k) s += red[k][t];
    atomicAdd(&sumsq[col0 + t], s);
  }
}

__global__ void finalize_kernel(
    const float* __restrict__ sums, const float* __restrict__ sumsq,
    const float* __restrict__ gamma, const float* __restrict__ beta,
    float* __restrict__ scale, float* __restrict__ shift, int N)
{
  int c = blockIdx.x * blockDim.x + threadIdx.x;
  if (c < DDEC) {
    float inv_n = 1.0f / (float)N;
    float mu = sums[c] * inv_n;
    float var = sumsq[c] * inv_n - mu * mu;
    float sc = gamma[c] * rsqrtf(var + 1e-5f);
    scale[c] = sc;
    shift[c] = beta[c] - mu * sc;
  }
}

// ------------------------------------------------- rec: fused d-recompute -> BN -> leaky -> @Wd2^T
__global__ __launch_bounds__(256) void rec_kernel(
    const float* __restrict__ h, const float* __restrict__ Wd1,
    const float* __restrict__ bd1,
    const float* __restrict__ scale, const float* __restrict__ shift,
    const float* __restrict__ Wd2, const float* __restrict__ bd2,
    float* __restrict__ rec, int N)
{
  __shared__ __align__(16) float hs[D][64];    // [k][row] 32KB
  __shared__ __align__(16) float dn[64][64];   // [c][row] 16KB
  __shared__ __align__(16) float W1s[16][64];  // [k][c]   4KB
  __shared__ __align__(16) float W2s[16][128]; // [cc][col] 8KB
  const int t = threadIdx.x;
  const int row0 = blockIdx.x * 64;
  const int ty1 = t >> 4, tx1 = t & 15;   // phase A: 4x4 over 64x64
  const int tyB = t >> 5, txB = t & 31;   // phase B: 8x4 over 64x128
  const int lr = t >> 2, lk = (t & 3) << 2;

#pragma unroll
  for (int rep = 0; rep < 8; ++rep) {
    int u = t + rep * 256;
    int r = u >> 5;
    int kb = (u & 31) << 2;
    float4 v = make_float4(0, 0, 0, 0);
    int row = row0 + r;
    if (row < N) v = *(const float4*)&h[(size_t)row * D + kb];
    hs[kb + 0][r] = v.x; hs[kb + 1][r] = v.y; hs[kb + 2][r] = v.z; hs[kb + 3][r] = v.w;
  }
  __syncthreads();

  float acc[8][4] = {};
  for (int c0 = 0; c0 < DDEC; c0 += 64) {
    // ---- phase A: dtile[64 rows][64 c] = hs @ Wd1[c0:c0+64]^T
    float dacc[4][4] = {};
    for (int k0 = 0; k0 < D; k0 += 16) {
      float4 w = *(const float4*)&Wd1[(size_t)(c0 + lr) * D + k0 + lk];
      __syncthreads();
      W1s[lk + 0][lr] = w.x; W1s[lk + 1][lr] = w.y; W1s[lk + 2][lr] = w.z; W1s[lk + 3][lr] = w.w;
      __syncthreads();
#pragma unroll
      for (int kk = 0; kk < 16; ++kk) {
        float4 v;
        v = *(const float4*)&hs[k0 + kk][ty1 << 2]; const float fa[4] = {v.x, v.y, v.z, v.w};
        v = *(const float4*)&W1s[kk][tx1 << 2];     const float fw[4] = {v.x, v.y, v.z, v.w};
#pragma unroll
        for (int i = 0; i < 4; ++i)
#pragma unroll
          for (int j = 0; j < 4; ++j)
            dacc[i][j] += fa[i] * fw[j];
      }
    }
    // ---- normalize + leaky into dn (transposed: dn[c][row])
#pragma unroll
    for (int j = 0; j < 4; ++j) {
      int cg = c0 + (tx1 << 2) + j;
      float bb = bd1[cg], sc = scale[cg], sh = shift[cg];
#pragma unroll
      for (int i = 0; i < 4; ++i) {
        float v = dacc[i][j] + bb;
        v = v * sc + sh;
        v = (v >= 0.f) ? v : 0.01f * v;
        dn[(tx1 << 2) + j][(ty1 << 2) + i] = v;
      }
    }
    // ---- phase B: acc += dn^T @ Wd2[:, c0:c0+64]^T
    for (int cc0 = 0; cc0 < 64; cc0 += 16) {
      int colA = t >> 2, ccb = (t & 3) << 2;
      float4 wa = *(const float4*)&Wd2[(size_t)colA * DDEC + c0 + cc0 + ccb];
      float4 wb = *(const float4*)&Wd2[(size_t)(colA + 64) * DDEC + c0 + cc0 + ccb];
      __syncthreads();
      W2s[ccb + 0][colA] = wa.x; W2s[ccb + 1][colA] = wa.y; W2s[ccb + 2][colA] = wa.z; W2s[ccb + 3][colA] = wa.w;
      W2s[ccb + 0][colA + 64] = wb.x; W2s[ccb + 1][colA + 64] = wb.y; W2s[ccb + 2][colA + 64] = wb.z; W2s[ccb + 3][colA + 64] = wb.w;
      __syncthreads();
#pragma unroll
      for (int cc = 0; cc < 16; ++cc) {
        float4 v;
        v = *(const float4*)&dn[cc0 + cc][tyB << 3];       const float a0[4] = {v.x, v.y, v.z, v.w};
        v = *(const float4*)&dn[cc0 + cc][(tyB << 3) + 4]; const float a1[4] = {v.x, v.y, v.z, v.w};
        v = *(const float4*)&W2s[cc][txB << 2];            const float w2[4] = {v.x, v.y, v.z, v.w};
#pragma unroll
        for (int j = 0; j < 4; ++j) {
#pragma unroll
          for (int i = 0; i < 4; ++i) {
            acc[i][j] += a0[i] * w2[j];
            acc[4 + i][j] += a1[i] * w2[j];
          }
        }
      }
    }
  }
  float4 bv = *(const float4*)&bd2[txB << 2];
  const float b2[4] = {bv.x, bv.y, bv.z, bv.w};
#pragma unroll
  for (int i = 0; i < 8; ++i) {
    int row = row0 + (tyB << 3) + i;
    if (row < N) {
      float4 r;
      r.x = acc[i][0] + b2[0];
      r.y = acc[i][1] + b2[1];
      r.z = acc[i][2] + b2[2];
      r.w = acc[i][3] + b2[3];
      *(float4*)&rec[(size_t)row * D + (txB << 2)] = r;
    }
  }
}

// ---------------------------------------------------------------- launch
extern "C" void kernel_launch(void* const* d_in, const int* in_sizes, int n_in,
                              void* d_out, int out_size, void* d_ws, size_t ws_size,
                              hipStream_t stream)
{
  const float* x   = (const float*)d_in[0];
  const int*   ei  = (const int*)d_in[1];
  const float* Wl  = (const float*)d_in[2];
  const float* bl  = (const float*)d_in[3];
  const float* Wr  = (const float*)d_in[4];
  const float* Wp  = (const float*)d_in[5];
  const float* bp  = (const float*)d_in[6];
  const float* ap  = (const float*)d_in[7];
  const float* Wd1 = (const float*)d_in[8];
  const float* bd1 = (const float*)d_in[9];
  const float* gm  = (const float*)d_in[10];
  const float* bt  = (const float*)d_in[11];
  const float* Wd2 = (const float*)d_in[12];
  const float* bd2 = (const float*)d_in[13];

  const int N = in_sizes[0] / D;   // 100000
  const int E = in_sizes[1] / 2;   // 1600000

  float* h_out   = (float*)d_out;
  float* z_out   = h_out + (size_t)N * D;
  float* rec_out = z_out + (size_t)N * D;
  float* tgt_out = rec_out + (size_t)N * D;

  // small scratch in ws (~9KB)
  float* sums  = (float*)d_ws;
  float* sumsq = sums + DDEC;
  float* scale = sumsq + DDEC;
  float* shift = scale + DDEC;
  int*   flag  = (int*)(shift + DDEC);
  int*   bsum  = flag + 1;  // 256 ints

  // big CSR scratch lives in the tgt output slot (written last)
  int* colidx = (int*)tgt_out;        // E ints
  int* deg    = colidx + E;           // N ints
  int* fillc  = deg + N;              // N ints
  int* rowptr = fillc + N;            // N+1 ints

  float* aggr = z_out;  // aggregated mean staged in z slot (z computed later)

  hipMemsetAsync(deg, 0, (size_t)2 * N * sizeof(int), stream);  // deg + fillc
  hipMemsetAsync(sums, 0, (size_t)2 * DDEC * sizeof(float), stream);

  detect_i64<<<1, 64, 0, stream>>>(ei, flag);

  int eb = (E + 255) / 256;
  count_deg<<<eb, 256, 0, stream>>>(ei, deg, flag, E);

  int NB = (N + 1023) / 1024;
  scan_reduce<<<NB, 256, 0, stream>>>(deg, bsum, N);
  scan_bsum<<<1, 256, 0, stream>>>(bsum, rowptr, NB, N, E);
  scan_final<<<NB, 256, 0, stream>>>(deg, bsum, rowptr, N);

  fill_csr<<<eb, 256, 0, stream>>>(ei, rowptr, fillc, colidx, flag, E);

  long long ag_threads = (long long)N * 64;
  aggregate_kernel<<<(int)((ag_threads + 255) / 256), 256, 0, stream>>>(
      rowptr, colidx, x, aggr, N);

  int rb = (N + 63) / 64;
  gemm_h_kernel<<<dim3(rb, 2), 256, 0, stream>>>(aggr, x, Wl, Wr, bl, h_out, N);

  gemm_dstat_kernel<<<dim3(rb, 8), 256, 0, stream>>>(h_out, Wd1, bd1, sums, sumsq, N);
  finalize_kernel<<<2, 256, 0, stream>>>(sums, sumsq, gm, bt, scale, shift, N);

  gemm_z_kernel<<<dim3(rb, 2), 256, 0, stream>>>(h_out, Wp, bp, ap, z_out, N);

  rec_kernel<<<rb, 256, 0, stream>>>(h_out, Wd1, bd1, scale, shift, Wd2, bd2, rec_out, N);

  hipMemcpyAsync(tgt_out, x, (size_t)N * D * sizeof(float), hipMemcpyDeviceToDevice, stream);
}

// Round 3
// 583.468 us; speedup vs baseline: 6.6627x; 2.2876x over previous
//
#include <hip/hip_runtime.h>
#include <cstdint>
#include <cstddef>

#define D 128
#define DDEC 512

typedef __attribute__((ext_vector_type(8))) short short8;
typedef __attribute__((ext_vector_type(4))) float f32x4;

__device__ __forceinline__ ushort f2bf(float f) {
  uint32_t u = __float_as_uint(f);
  u = u + 0x7FFF + ((u >> 16) & 1);   // round-to-nearest-even
  return (ushort)(u >> 16);
}

// ---------------------------------------------------------------- utils
__global__ void detect_i64(const int* __restrict__ ei, int* __restrict__ flag) {
  if (threadIdx.x == 0 && blockIdx.x == 0) {
    int allz = 1;
    for (int k = 0; k < 64; ++k)
      if (ei[2 * k + 1] != 0) { allz = 0; break; }
    *flag = allz ? 2 : 1;  // 2 => int64 storage read as int32 pairs
  }
}

// ---------------------------------------------------------------- CSR build
__global__ __launch_bounds__(256) void count_deg(
    const int* __restrict__ ei, int* __restrict__ deg,
    const int* __restrict__ flag, int E)
{
  int e = blockIdx.x * 256 + threadIdx.x;
  if (e >= E) return;
  int s = *flag;
  int dst = ei[((long long)E + e) * s];
  atomicAdd(&deg[dst], 1);
}

__global__ __launch_bounds__(256) void scan_reduce(
    const int* __restrict__ deg, int* __restrict__ bsum, int N)
{
  __shared__ int red[256];
  int base = blockIdx.x * 1024 + threadIdx.x * 4;
  int s = 0;
#pragma unroll
  for (int k = 0; k < 4; ++k) { int i = base + k; if (i < N) s += deg[i]; }
  red[threadIdx.x] = s;
  __syncthreads();
  for (int off = 128; off > 0; off >>= 1) {
    if (threadIdx.x < off) red[threadIdx.x] += red[threadIdx.x + off];
    __syncthreads();
  }
  if (threadIdx.x == 0) bsum[blockIdx.x] = red[0];
}

__global__ void scan_bsum(int* __restrict__ bsum, int* __restrict__ rowptr,
                          int NB, int N, int E)
{
  __shared__ int tmp[256];
  int t = threadIdx.x;
  int v = (t < NB) ? bsum[t] : 0;
  tmp[t] = v;
  __syncthreads();
  for (int off = 1; off < 256; off <<= 1) {
    int add = (t >= off) ? tmp[t - off] : 0;
    __syncthreads();
    tmp[t] += add;
    __syncthreads();
  }
  if (t < NB) bsum[t] = tmp[t] - v;  // exclusive
  if (t == 0) rowptr[N] = E;
}

__global__ __launch_bounds__(256) void scan_final(
    const int* __restrict__ deg, const int* __restrict__ bsum,
    int* __restrict__ rowptr, int N)
{
  __shared__ int tsum[256];
  int base = blockIdx.x * 1024 + threadIdx.x * 4;
  int loc[4]; int s = 0;
#pragma unroll
  for (int k = 0; k < 4; ++k) { int i = base + k; loc[k] = (i < N) ? deg[i] : 0; s += loc[k]; }
  tsum[threadIdx.x] = s;
  __syncthreads();
  for (int off = 1; off < 256; off <<= 1) {
    int add = (threadIdx.x >= off) ? tsum[threadIdx.x - off] : 0;
    __syncthreads();
    tsum[threadIdx.x] += add;
    __syncthreads();
  }
  int excl = tsum[threadIdx.x] - s + bsum[blockIdx.x];
#pragma unroll
  for (int k = 0; k < 4; ++k) {
    int i = base + k;
    if (i < N) { rowptr[i] = excl; excl += loc[k]; }
  }
}

__global__ __launch_bounds__(256) void fill_csr(
    const int* __restrict__ ei, const int* __restrict__ rowptr,
    int* __restrict__ fillc, int* __restrict__ colidx,
    const int* __restrict__ flag, int E)
{
  int e = blockIdx.x * 256 + threadIdx.x;
  if (e >= E) return;
  int s = *flag;
  int src = ei[(long long)e * s];
  int dst = ei[((long long)E + e) * s];
  int pos = rowptr[dst] + atomicAdd(&fillc[dst], 1);
  colidx[pos] = src;
}

// ---------------------------------------------------------------- gather-mean
__global__ __launch_bounds__(256) void aggregate_kernel(
    const int* __restrict__ rowptr, const int* __restrict__ colidx,
    const float* __restrict__ x, float* __restrict__ aggr, int N)
{
  int wave = (blockIdx.x * 256 + threadIdx.x) >> 6;
  int lane = threadIdx.x & 63;
  if (wave >= N) return;
  int s = rowptr[wave], epos = rowptr[wave + 1];
  float2 acc = make_float2(0.f, 0.f);
  int e = s;
  for (; e + 1 < epos; e += 2) {
    int s0 = colidx[e], s1 = colidx[e + 1];
    const float2 v0 = *(const float2*)&x[(size_t)s0 * D + lane * 2];
    const float2 v1 = *(const float2*)&x[(size_t)s1 * D + lane * 2];
    acc.x += v0.x + v1.x;
    acc.y += v0.y + v1.y;
  }
  if (e < epos) {
    int s0 = colidx[e];
    const float2 v0 = *(const float2*)&x[(size_t)s0 * D + lane * 2];
    acc.x += v0.x;
    acc.y += v0.y;
  }
  int degn = epos - s;
  float inv = 1.0f / (float)(degn > 0 ? degn : 1);
  acc.x *= inv; acc.y *= inv;
  *(float2*)&aggr[(size_t)wave * D + lane * 2] = acc;
}

// ---------------------------------------------------------------- weight f32->bf16
__global__ __launch_bounds__(256) void wcvt_kernel(
    const float* __restrict__ Wl, const float* __restrict__ Wr,
    const float* __restrict__ Wp, const float* __restrict__ Wd1,
    const float* __restrict__ Wd2, ushort* __restrict__ wb)
{
  int i = blockIdx.x * 256 + threadIdx.x;
  if (i >= 180224) return;
  float v;
  if (i < 16384) v = Wl[i];
  else if (i < 32768) v = Wr[i - 16384];
  else if (i < 49152) v = Wp[i - 32768];
  else if (i < 114688) v = Wd1[i - 49152];
  else v = Wd2[i - 114688];
  wb[i] = f2bf(v);
}

// ---------------------------------------------------------------- MFMA helpers
// stage 128 rows x 128 cols f32 -> LDS bf16 [128][136] (+16B row pad)
__device__ __forceinline__ void stage128(const float* __restrict__ src, int N,
                                         int row0, ushort* lds, int t)
{
#pragma unroll
  for (int p = 0; p < 8; ++p) {
    int r = (t >> 4) + p * 16;
    int c = (t & 15) * 8;
    short8 v = {};
    int row = row0 + r;
    if (row < N) {
      const float* s = src + (size_t)row * D + c;
      float4 f0 = *(const float4*)s;
      float4 f1 = *(const float4*)(s + 4);
      v[0] = (short)f2bf(f0.x); v[1] = (short)f2bf(f0.y);
      v[2] = (short)f2bf(f0.z); v[3] = (short)f2bf(f0.w);
      v[4] = (short)f2bf(f1.x); v[5] = (short)f2bf(f1.y);
      v[6] = (short)f2bf(f1.z); v[7] = (short)f2bf(f1.w);
    }
    *(short8*)&lds[r * 136 + c] = v;
  }
}

// one wave: 64x64 out tile, K=128. aLds pre-offset to wave's rows ([.][136] bf16),
// bGlb pre-offset to wave's cols (row-major [outcol][bld] bf16).
__device__ __forceinline__ void mma_tile(const ushort* __restrict__ aLds,
                                         const ushort* __restrict__ bGlb, size_t bld,
                                         f32x4 acc[4][4], int lane)
{
  const int r = lane & 15, g = lane >> 4;
#pragma unroll
  for (int ks = 0; ks < 4; ++ks) {
    short8 a[4], b[4];
#pragma unroll
    for (int m = 0; m < 4; ++m)
      a[m] = *(const short8*)&aLds[(m * 16 + r) * 136 + ks * 32 + g * 8];
#pragma unroll
    for (int n = 0; n < 4; ++n)
      b[n] = *(const short8*)&bGlb[(size_t)(n * 16 + r) * bld + ks * 32 + g * 8];
#pragma unroll
    for (int m = 0; m < 4; ++m)
#pragma unroll
      for (int n = 0; n < 4; ++n)
        acc[m][n] = __builtin_amdgcn_mfma_f32_16x16x32_bf16(a[m], b[n], acc[m][n], 0, 0, 0);
  }
}

// ------------------------------------------------- h = leaky(aggr@Wl^T + bl + x@Wr^T, 0.5)
__global__ __launch_bounds__(256, 2) void gemm_h_mfma(
    const float* __restrict__ aggr, const float* __restrict__ x,
    const ushort* __restrict__ Wlb, const ushort* __restrict__ Wrb,
    const float* __restrict__ bl, float* __restrict__ h, int N)
{
  __shared__ ushort As1[128 * 136];
  __shared__ ushort As2[128 * 136];
  const int t = threadIdx.x;
  const int row0 = blockIdx.x * 128;
  stage128(aggr, N, row0, As1, t);
  stage128(x, N, row0, As2, t);
  __syncthreads();
  const int lane = t & 63, w = t >> 6;
  const int wm = w >> 1, wn = w & 1;
  f32x4 acc[4][4] = {};
  mma_tile(As1 + wm * 64 * 136, Wlb + (size_t)(wn * 64) * D, D, acc, lane);
  mma_tile(As2 + wm * 64 * 136, Wrb + (size_t)(wn * 64) * D, D, acc, lane);
  const int g = lane >> 4, cr = lane & 15;
#pragma unroll
  for (int n = 0; n < 4; ++n) {
    int col = wn * 64 + n * 16 + cr;
    float b = bl[col];
#pragma unroll
    for (int m = 0; m < 4; ++m)
#pragma unroll
      for (int rr = 0; rr < 4; ++rr) {
        int row = row0 + wm * 64 + m * 16 + g * 4 + rr;
        if (row < N) {
          float v = acc[m][n][rr] + b;
          h[(size_t)row * D + col] = (v >= 0.f) ? v : 0.5f * v;
        }
      }
  }
}

// ------------------------------------------------- z = prelu(h@Wp^T + bp, a)
__global__ __launch_bounds__(256, 2) void gemm_z_mfma(
    const float* __restrict__ h, const ushort* __restrict__ Wpb,
    const float* __restrict__ bp, const float* __restrict__ ap,
    float* __restrict__ z, int N)
{
  __shared__ ushort As[128 * 136];
  const int t = threadIdx.x;
  const int row0 = blockIdx.x * 128;
  stage128(h, N, row0, As, t);
  __syncthreads();
  const int lane = t & 63, w = t >> 6;
  const int wm = w >> 1, wn = w & 1;
  f32x4 acc[4][4] = {};
  mma_tile(As + wm * 64 * 136, Wpb + (size_t)(wn * 64) * D, D, acc, lane);
  const float alpha = ap[0];
  const int g = lane >> 4, cr = lane & 15;
#pragma unroll
  for (int n = 0; n < 4; ++n) {
    int col = wn * 64 + n * 16 + cr;
    float b = bp[col];
#pragma unroll
    for (int m = 0; m < 4; ++m)
#pragma unroll
      for (int rr = 0; rr < 4; ++rr) {
        int row = row0 + wm * 64 + m * 16 + g * 4 + rr;
        if (row < N) {
          float v = acc[m][n][rr] + b;
          z[(size_t)row * D + col] = (v >= 0.f) ? v : alpha * v;
        }
      }
  }
}

// ------------------------------------------------- BN stats of d = h@Wd1^T + bd1
__global__ __launch_bounds__(256, 2) void dstat_mfma(
    const float* __restrict__ h, const ushort* __restrict__ Wd1b,
    const float* __restrict__ bd1,
    float* __restrict__ sums, float* __restrict__ sumsq, int N)
{
  __shared__ ushort As[128 * 136];
  __shared__ float part1[8][132];
  __shared__ float part2[8][132];
  const int t = threadIdx.x;
  const int row0 = blockIdx.x * 128;
  const int col0 = blockIdx.y * 128;
  stage128(h, N, row0, As, t);
  __syncthreads();
  const int lane = t & 63, w = t >> 6;
  const int wm = w >> 1, wn = w & 1;
  f32x4 acc[4][4] = {};
  mma_tile(As + wm * 64 * 136, Wd1b + (size_t)(col0 + wn * 64) * D, D, acc, lane);
  const int g = lane >> 4, cr = lane & 15;
#pragma unroll
  for (int n = 0; n < 4; ++n) {
    int col = col0 + wn * 64 + n * 16 + cr;
    float b = bd1[col];
    float s1 = 0.f, s2 = 0.f;
#pragma unroll
    for (int m = 0; m < 4; ++m)
#pragma unroll
      for (int rr = 0; rr < 4; ++rr) {
        int row = row0 + wm * 64 + m * 16 + g * 4 + rr;
        if (row < N) {
          float v = acc[m][n][rr] + b;
          s1 += v; s2 += v * v;
        }
      }
    part1[wm * 4 + g][wn * 64 + n * 16 + cr] = s1;
    part2[wm * 4 + g][wn * 64 + n * 16 + cr] = s2;
  }
  __syncthreads();
  if (t < 128) {
    float s = 0;
#pragma unroll
    for (int k = 0; k < 8; ++k) s += part1[k][t];
    atomicAdd(&sums[col0 + t], s);
  } else {
    int c = t - 128;
    float s = 0;
#pragma unroll
    for (int k = 0; k < 8; ++k) s += part2[k][c];
    atomicAdd(&sumsq[col0 + c], s);
  }
}

__global__ void finalize_kernel(
    const float* __restrict__ sums, const float* __restrict__ sumsq,
    const float* __restrict__ gamma, const float* __restrict__ beta,
    float* __restrict__ scale, float* __restrict__ shift, int N)
{
  int c = blockIdx.x * blockDim.x + threadIdx.x;
  if (c < DDEC) {
    float inv_n = 1.0f / (float)N;
    float mu = sums[c] * inv_n;
    float var = sumsq[c] * inv_n - mu * mu;
    float sc = gamma[c] * rsqrtf(var + 1e-5f);
    scale[c] = sc;
    shift[c] = beta[c] - mu * sc;
  }
}

// ------------------------------------------------- rec: d-recompute -> BN -> leaky -> @Wd2^T
__global__ __launch_bounds__(256, 2) void rec_mfma(
    const float* __restrict__ h, const ushort* __restrict__ Wd1b,
    const ushort* __restrict__ Wd2b, const float* __restrict__ bd1,
    const float* __restrict__ scale, const float* __restrict__ shift,
    const float* __restrict__ bd2, float* __restrict__ rec, int N)
{
  __shared__ ushort Hs[128 * 136];
  __shared__ ushort Dn[128 * 136];
  const int t = threadIdx.x;
  const int row0 = blockIdx.x * 128;
  stage128(h, N, row0, Hs, t);
  const int lane = t & 63, w = t >> 6;
  const int wm = w >> 1, wn = w & 1;
  const int g = lane >> 4, cr = lane & 15;
  f32x4 acc[4][4] = {};
  __syncthreads();
  for (int c0 = 0; c0 < DDEC; c0 += 128) {
    f32x4 dacc[4][4] = {};
    mma_tile(Hs + wm * 64 * 136, Wd1b + (size_t)(c0 + wn * 64) * D, D, dacc, lane);
    __syncthreads();  // previous chunk's Dn reads complete before overwrite
#pragma unroll
    for (int n = 0; n < 4; ++n) {
      int lc = wn * 64 + n * 16 + cr;
      int c = c0 + lc;
      float bb = bd1[c], sc = scale[c], sh = shift[c];
#pragma unroll
      for (int m = 0; m < 4; ++m)
#pragma unroll
        for (int rr = 0; rr < 4; ++rr) {
          float v = dacc[m][n][rr] + bb;
          v = v * sc + sh;
          v = (v >= 0.f) ? v : 0.01f * v;
          Dn[(wm * 64 + m * 16 + g * 4 + rr) * 136 + lc] = f2bf(v);
        }
    }
    __syncthreads();
    mma_tile(Dn + wm * 64 * 136, Wd2b + (size_t)(wn * 64) * DDEC + c0, DDEC, acc, lane);
  }
#pragma unroll
  for (int n = 0; n < 4; ++n) {
    int col = wn * 64 + n * 16 + cr;
    float b = bd2[col];
#pragma unroll
    for (int m = 0; m < 4; ++m)
#pragma unroll
      for (int rr = 0; rr < 4; ++rr) {
        int row = row0 + wm * 64 + m * 16 + g * 4 + rr;
        if (row < N) rec[(size_t)row * D + col] = acc[m][n][rr] + b;
      }
  }
}

// ---------------------------------------------------------------- launch
extern "C" void kernel_launch(void* const* d_in, const int* in_sizes, int n_in,
                              void* d_out, int out_size, void* d_ws, size_t ws_size,
                              hipStream_t stream)
{
  const float* x   = (const float*)d_in[0];
  const int*   ei  = (const int*)d_in[1];
  const float* Wl  = (const float*)d_in[2];
  const float* bl  = (const float*)d_in[3];
  const float* Wr  = (const float*)d_in[4];
  const float* Wp  = (const float*)d_in[5];
  const float* bp  = (const float*)d_in[6];
  const float* ap  = (const float*)d_in[7];
  const float* Wd1 = (const float*)d_in[8];
  const float* bd1 = (const float*)d_in[9];
  const float* gm  = (const float*)d_in[10];
  const float* bt  = (const float*)d_in[11];
  const float* Wd2 = (const float*)d_in[12];
  const float* bd2 = (const float*)d_in[13];

  const int N = in_sizes[0] / D;   // 100000
  const int E = in_sizes[1] / 2;   // 1600000

  float* h_out   = (float*)d_out;
  float* z_out   = h_out + (size_t)N * D;
  float* rec_out = z_out + (size_t)N * D;
  float* tgt_out = rec_out + (size_t)N * D;

  // small scratch in ws (~9KB)
  float* sums  = (float*)d_ws;
  float* sumsq = sums + DDEC;
  float* scale = sumsq + DDEC;
  float* shift = scale + DDEC;
  int*   flag  = (int*)(shift + DDEC);
  int*   bsum  = flag + 1;  // 256 ints

  // big scratch lives in the tgt output slot (written last)
  int* colidx = (int*)tgt_out;        // E ints (~6.4MB)
  int* deg    = colidx + E;           // N ints
  int* fillc  = deg + N;              // N ints
  int* rowptr = fillc + N;            // N+1 ints  (head usage ~7.6MB)
  ushort* wb  = (ushort*)(tgt_out + 11000000);  // bf16 weights, 352KB @ +44MB
  ushort* Wlb  = wb;
  ushort* Wrb  = wb + 16384;
  ushort* Wpb  = wb + 32768;
  ushort* Wd1b = wb + 49152;
  ushort* Wd2b = wb + 114688;

  float* aggr = z_out;  // aggregated mean staged in z slot (z computed later)

  hipMemsetAsync(deg, 0, (size_t)2 * N * sizeof(int), stream);  // deg + fillc
  hipMemsetAsync(sums, 0, (size_t)2 * DDEC * sizeof(float), stream);

  detect_i64<<<1, 64, 0, stream>>>(ei, flag);
  wcvt_kernel<<<704, 256, 0, stream>>>(Wl, Wr, Wp, Wd1, Wd2, wb);

  int eb = (E + 255) / 256;
  count_deg<<<eb, 256, 0, stream>>>(ei, deg, flag, E);

  int NB = (N + 1023) / 1024;
  scan_reduce<<<NB, 256, 0, stream>>>(deg, bsum, N);
  scan_bsum<<<1, 256, 0, stream>>>(bsum, rowptr, NB, N, E);
  scan_final<<<NB, 256, 0, stream>>>(deg, bsum, rowptr, N);

  fill_csr<<<eb, 256, 0, stream>>>(ei, rowptr, fillc, colidx, flag, E);

  long long ag_threads = (long long)N * 64;
  aggregate_kernel<<<(int)((ag_threads + 255) / 256), 256, 0, stream>>>(
      rowptr, colidx, x, aggr, N);

  int rb = (N + 127) / 128;
  gemm_h_mfma<<<rb, 256, 0, stream>>>(aggr, x, Wlb, Wrb, bl, h_out, N);

  dstat_mfma<<<dim3(rb, 4), 256, 0, stream>>>(h_out, Wd1b, bd1, sums, sumsq, N);
  finalize_kernel<<<2, 256, 0, stream>>>(sums, sumsq, gm, bt, scale, shift, N);

  rec_mfma<<<rb, 256, 0, stream>>>(h_out, Wd1b, Wd2b, bd1, scale, shift, bd2, rec_out, N);

  gemm_z_mfma<<<rb, 256, 0, stream>>>(h_out, Wpb, bp, ap, z_out, N);

  hipMemcpyAsync(tgt_out, x, (size_t)N * D * sizeof(float), hipMemcpyDeviceToDevice, stream);
}

// Round 4
// 550.916 us; speedup vs baseline: 7.0564x; 1.0591x over previous
//
#include <hip/hip_runtime.h>
#include <cstdint>
#include <cstddef>

#define D 128
#define DDEC 512

typedef __attribute__((ext_vector_type(8))) short short8;
typedef __attribute__((ext_vector_type(4))) float f32x4;

__device__ __forceinline__ ushort f2bf(float f) {
  uint32_t u = __float_as_uint(f);
  u = u + 0x7FFF + ((u >> 16) & 1);   // round-to-nearest-even
  return (ushort)(u >> 16);
}

// ---------------------------------------------------------------- utils
__global__ void detect_i64(const int* __restrict__ ei, int* __restrict__ flag) {
  if (threadIdx.x == 0 && blockIdx.x == 0) {
    int allz = 1;
    for (int k = 0; k < 64; ++k)
      if (ei[2 * k + 1] != 0) { allz = 0; break; }
    *flag = allz ? 2 : 1;  // 2 => int64 storage read as int32 pairs
  }
}

// ---------------------------------------------------------------- CSR build
__global__ __launch_bounds__(256) void count_deg(
    const int* __restrict__ ei, int* __restrict__ deg,
    const int* __restrict__ flag, int E)
{
  int e = blockIdx.x * 256 + threadIdx.x;
  if (e >= E) return;
  int s = *flag;
  int dst = ei[((long long)E + e) * s];
  atomicAdd(&deg[dst], 1);
}

__global__ __launch_bounds__(256) void scan_reduce(
    const int* __restrict__ deg, int* __restrict__ bsum, int N)
{
  __shared__ int red[256];
  int base = blockIdx.x * 1024 + threadIdx.x * 4;
  int s = 0;
#pragma unroll
  for (int k = 0; k < 4; ++k) { int i = base + k; if (i < N) s += deg[i]; }
  red[threadIdx.x] = s;
  __syncthreads();
  for (int off = 128; off > 0; off >>= 1) {
    if (threadIdx.x < off) red[threadIdx.x] += red[threadIdx.x + off];
    __syncthreads();
  }
  if (threadIdx.x == 0) bsum[blockIdx.x] = red[0];
}

__global__ void scan_bsum(int* __restrict__ bsum, int* __restrict__ rowptr,
                          int NB, int N, int E)
{
  __shared__ int tmp[256];
  int t = threadIdx.x;
  int v = (t < NB) ? bsum[t] : 0;
  tmp[t] = v;
  __syncthreads();
  for (int off = 1; off < 256; off <<= 1) {
    int add = (t >= off) ? tmp[t - off] : 0;
    __syncthreads();
    tmp[t] += add;
    __syncthreads();
  }
  if (t < NB) bsum[t] = tmp[t] - v;  // exclusive
  if (t == 0) rowptr[N] = E;
}

__global__ __launch_bounds__(256) void scan_final(
    const int* __restrict__ deg, const int* __restrict__ bsum,
    int* __restrict__ rowptr, int N)
{
  __shared__ int tsum[256];
  int base = blockIdx.x * 1024 + threadIdx.x * 4;
  int loc[4]; int s = 0;
#pragma unroll
  for (int k = 0; k < 4; ++k) { int i = base + k; loc[k] = (i < N) ? deg[i] : 0; s += loc[k]; }
  tsum[threadIdx.x] = s;
  __syncthreads();
  for (int off = 1; off < 256; off <<= 1) {
    int add = (threadIdx.x >= off) ? tsum[threadIdx.x - off] : 0;
    __syncthreads();
    tsum[threadIdx.x] += add;
    __syncthreads();
  }
  int excl = tsum[threadIdx.x] - s + bsum[blockIdx.x];
#pragma unroll
  for (int k = 0; k < 4; ++k) {
    int i = base + k;
    if (i < N) { rowptr[i] = excl; excl += loc[k]; }
  }
}

__global__ __launch_bounds__(256) void fill_csr(
    const int* __restrict__ ei, const int* __restrict__ rowptr,
    int* __restrict__ fillc, int* __restrict__ colidx,
    const int* __restrict__ flag, int E)
{
  int e = blockIdx.x * 256 + threadIdx.x;
  if (e >= E) return;
  int s = *flag;
  int src = ei[(long long)e * s];
  int dst = ei[((long long)E + e) * s];
  int pos = rowptr[dst] + atomicAdd(&fillc[dst], 1);
  colidx[pos] = src;
}

// ---------------------------------------------------------------- conversions
__global__ __launch_bounds__(256) void xcvt_kernel(
    const float* __restrict__ x, ushort* __restrict__ xb, int n8)
{
  int i = blockIdx.x * 256 + threadIdx.x;
  if (i >= n8) return;
  const float* s = x + (size_t)i * 8;
  float4 f0 = *(const float4*)s;
  float4 f1 = *(const float4*)(s + 4);
  short8 v;
  v[0] = (short)f2bf(f0.x); v[1] = (short)f2bf(f0.y);
  v[2] = (short)f2bf(f0.z); v[3] = (short)f2bf(f0.w);
  v[4] = (short)f2bf(f1.x); v[5] = (short)f2bf(f1.y);
  v[6] = (short)f2bf(f1.z); v[7] = (short)f2bf(f1.w);
  *(short8*)&xb[(size_t)i * 8] = v;
}

__global__ __launch_bounds__(256) void wcvt_kernel(
    const float* __restrict__ Wl, const float* __restrict__ Wr,
    const float* __restrict__ Wp, const float* __restrict__ Wd1,
    const float* __restrict__ Wd2, ushort* __restrict__ wb)
{
  int i = blockIdx.x * 256 + threadIdx.x;
  if (i >= 180224) return;
  float v;
  if (i < 16384) v = Wl[i];
  else if (i < 32768) v = Wr[i - 16384];
  else if (i < 49152) v = Wp[i - 32768];
  else if (i < 114688) v = Wd1[i - 49152];
  else v = Wd2[i - 114688];
  wb[i] = f2bf(v);
}

// ---------------------------------------------------------------- gather-mean (bf16)
__global__ __launch_bounds__(256) void aggregate_kernel(
    const int* __restrict__ rowptr, const int* __restrict__ colidx,
    const ushort* __restrict__ xb, ushort* __restrict__ aggrb, int N)
{
  int wave = (blockIdx.x * 256 + threadIdx.x) >> 6;
  int lane = threadIdx.x & 63;
  if (wave >= N) return;
  int s = rowptr[wave], epos = rowptr[wave + 1];
  float ax = 0.f, ay = 0.f;
  int e = s;
  for (; e + 1 < epos; e += 2) {
    int s0 = colidx[e], s1 = colidx[e + 1];
    uint u0 = *(const uint*)&xb[(size_t)s0 * D + lane * 2];
    uint u1 = *(const uint*)&xb[(size_t)s1 * D + lane * 2];
    ax += __uint_as_float(u0 << 16) + __uint_as_float(u1 << 16);
    ay += __uint_as_float(u0 & 0xFFFF0000u) + __uint_as_float(u1 & 0xFFFF0000u);
  }
  if (e < epos) {
    uint u0 = *(const uint*)&xb[(size_t)colidx[e] * D + lane * 2];
    ax += __uint_as_float(u0 << 16);
    ay += __uint_as_float(u0 & 0xFFFF0000u);
  }
  int degn = epos - s;
  float inv = 1.0f / (float)(degn > 0 ? degn : 1);
  uint out = ((uint)f2bf(ax * inv)) | (((uint)f2bf(ay * inv)) << 16);
  *(uint*)&aggrb[(size_t)wave * D + lane * 2] = out;
}

// ---------------------------------------------------------------- MFMA helpers
// A from global (row-major, stride ald), B from global (row-major, stride bld)
__device__ __forceinline__ void mma_tile_g(const ushort* __restrict__ A, size_t ald,
                                           const ushort* __restrict__ B, size_t bld,
                                           f32x4 acc[4][4], int lane)
{
  const int r = lane & 15, g = lane >> 4;
#pragma unroll
  for (int ks = 0; ks < 4; ++ks) {
    short8 a[4], b[4];
#pragma unroll
    for (int m = 0; m < 4; ++m)
      a[m] = *(const short8*)&A[(size_t)(m * 16 + r) * ald + ks * 32 + g * 8];
#pragma unroll
    for (int n = 0; n < 4; ++n)
      b[n] = *(const short8*)&B[(size_t)(n * 16 + r) * bld + ks * 32 + g * 8];
#pragma unroll
    for (int m = 0; m < 4; ++m)
#pragma unroll
      for (int n = 0; n < 4; ++n)
        acc[m][n] = __builtin_amdgcn_mfma_f32_16x16x32_bf16(a[m], b[n], acc[m][n], 0, 0, 0);
  }
}

// A from LDS (stride 136), B from global
__device__ __forceinline__ void mma_tile_l(const ushort* aLds,
                                           const ushort* __restrict__ bGlb, size_t bld,
                                           f32x4 acc[4][4], int lane)
{
  const int r = lane & 15, g = lane >> 4;
#pragma unroll
  for (int ks = 0; ks < 4; ++ks) {
    short8 a[4], b[4];
#pragma unroll
    for (int m = 0; m < 4; ++m)
      a[m] = *(const short8*)&aLds[(m * 16 + r) * 136 + ks * 32 + g * 8];
#pragma unroll
    for (int n = 0; n < 4; ++n)
      b[n] = *(const short8*)&bGlb[(size_t)(n * 16 + r) * bld + ks * 32 + g * 8];
#pragma unroll
    for (int m = 0; m < 4; ++m)
#pragma unroll
      for (int n = 0; n < 4; ++n)
        acc[m][n] = __builtin_amdgcn_mfma_f32_16x16x32_bf16(a[m], b[n], acc[m][n], 0, 0, 0);
  }
}

// stage 128x128 f32 -> LDS bf16 [128][136] (for gemm_z only)
__device__ __forceinline__ void stage128(const float* __restrict__ src, int N,
                                         int row0, ushort* lds, int t)
{
#pragma unroll
  for (int p = 0; p < 8; ++p) {
    int r = (t >> 4) + p * 16;
    int c = (t & 15) * 8;
    short8 v = {};
    int row = row0 + r;
    if (row < N) {
      const float* s = src + (size_t)row * D + c;
      float4 f0 = *(const float4*)s;
      float4 f1 = *(const float4*)(s + 4);
      v[0] = (short)f2bf(f0.x); v[1] = (short)f2bf(f0.y);
      v[2] = (short)f2bf(f0.z); v[3] = (short)f2bf(f0.w);
      v[4] = (short)f2bf(f1.x); v[5] = (short)f2bf(f1.y);
      v[6] = (short)f2bf(f1.z); v[7] = (short)f2bf(f1.w);
    }
    *(short8*)&lds[r * 136 + c] = v;
  }
}

// ------------------------------------------------- h = leaky(aggr@Wl^T + bl + x@Wr^T, 0.5)
// no LDS: A fragments direct from global bf16; writes h (f32) and hb (bf16)
__global__ __launch_bounds__(256, 2) void gemm_h_mfma(
    const ushort* __restrict__ aggrb, const ushort* __restrict__ xb,
    const ushort* __restrict__ Wlb, const ushort* __restrict__ Wrb,
    const float* __restrict__ bl, float* __restrict__ h,
    ushort* __restrict__ hb, int N)
{
  const int t = threadIdx.x;
  const int row0 = blockIdx.x * 128;
  const int lane = t & 63, w = t >> 6;
  const int wm = w >> 1, wn = w & 1;
  f32x4 acc[4][4] = {};
  mma_tile_g(aggrb + (size_t)(row0 + wm * 64) * D, D, Wlb + (size_t)(wn * 64) * D, D, acc, lane);
  mma_tile_g(xb + (size_t)(row0 + wm * 64) * D, D, Wrb + (size_t)(wn * 64) * D, D, acc, lane);
  const int g = lane >> 4, cr = lane & 15;
#pragma unroll
  for (int n = 0; n < 4; ++n) {
    int col = wn * 64 + n * 16 + cr;
    float b = bl[col];
#pragma unroll
    for (int m = 0; m < 4; ++m)
#pragma unroll
      for (int rr = 0; rr < 4; ++rr) {
        int row = row0 + wm * 64 + m * 16 + g * 4 + rr;
        if (row < N) {
          float v = acc[m][n][rr] + b;
          v = (v >= 0.f) ? v : 0.5f * v;
          h[(size_t)row * D + col] = v;
          hb[(size_t)row * D + col] = f2bf(v);
        }
      }
  }
}

// ------------------------------------------------- BN stats of d = hb@Wd1^T + bd1 (all 512 cols)
__global__ __launch_bounds__(256, 2) void dstat_mfma(
    const ushort* __restrict__ hb, const ushort* __restrict__ Wd1b,
    const float* __restrict__ bd1,
    float* __restrict__ sums, float* __restrict__ sumsq, int N)
{
  __shared__ float part1[8][132];
  __shared__ float part2[8][132];
  const int t = threadIdx.x;
  const int row0 = blockIdx.x * 128;
  const int lane = t & 63, w = t >> 6;
  const int wm = w >> 1, wn = w & 1;
  const int g = lane >> 4, cr = lane & 15;
  for (int c0 = 0; c0 < DDEC; c0 += 128) {
    f32x4 dacc[4][4] = {};
    mma_tile_g(hb + (size_t)(row0 + wm * 64) * D, D,
               Wd1b + (size_t)(c0 + wn * 64) * D, D, dacc, lane);
#pragma unroll
    for (int n = 0; n < 4; ++n) {
      int col = c0 + wn * 64 + n * 16 + cr;
      float b = bd1[col];
      float s1 = 0.f, s2 = 0.f;
#pragma unroll
      for (int m = 0; m < 4; ++m)
#pragma unroll
        for (int rr = 0; rr < 4; ++rr) {
          int row = row0 + wm * 64 + m * 16 + g * 4 + rr;
          if (row < N) {
            float v = dacc[m][n][rr] + b;
            s1 += v; s2 += v * v;
          }
        }
      part1[wm * 4 + g][wn * 64 + n * 16 + cr] = s1;
      part2[wm * 4 + g][wn * 64 + n * 16 + cr] = s2;
    }
    __syncthreads();
    if (t < 128) {
      float s = 0;
#pragma unroll
      for (int k = 0; k < 8; ++k) s += part1[k][t];
      atomicAdd(&sums[c0 + t], s);
    } else {
      int c = t - 128;
      float s = 0;
#pragma unroll
      for (int k = 0; k < 8; ++k) s += part2[k][c];
      atomicAdd(&sumsq[c0 + c], s);
    }
    __syncthreads();
  }
}

__global__ void finalize_kernel(
    const float* __restrict__ sums, const float* __restrict__ sumsq,
    const float* __restrict__ gamma, const float* __restrict__ beta,
    float* __restrict__ scale, float* __restrict__ shift, int N)
{
  int c = blockIdx.x * blockDim.x + threadIdx.x;
  if (c < DDEC) {
    float inv_n = 1.0f / (float)N;
    float mu = sums[c] * inv_n;
    float var = sumsq[c] * inv_n - mu * mu;
    float sc = gamma[c] * rsqrtf(var + 1e-5f);
    scale[c] = sc;
    shift[c] = beta[c] - mu * sc;
  }
}

// ------------------------------------------------- rec: d-recompute -> BN -> leaky -> @Wd2^T
__global__ __launch_bounds__(256, 2) void rec_mfma(
    const ushort* __restrict__ hb, const ushort* __restrict__ Wd1b,
    const ushort* __restrict__ Wd2b, const float* __restrict__ bd1,
    const float* __restrict__ scale, const float* __restrict__ shift,
    const float* __restrict__ bd2, float* __restrict__ rec, int N)
{
  __shared__ ushort Hs[128 * 136];
  __shared__ ushort Dn[128 * 136];
  const int t = threadIdx.x;
  const int row0 = blockIdx.x * 128;
  // stage hb tile (plain bf16 copy)
#pragma unroll
  for (int p = 0; p < 8; ++p) {
    int idx = t + p * 256;
    int r = idx >> 4, c = (idx & 15) * 8;
    short8 v = *(const short8*)&hb[(size_t)(row0 + r) * D + c];
    *(short8*)&Hs[r * 136 + c] = v;
  }
  const int lane = t & 63, w = t >> 6;
  const int wm = w >> 1, wn = w & 1;
  const int g = lane >> 4, cr = lane & 15;
  f32x4 acc[4][4] = {};
  __syncthreads();
  for (int c0 = 0; c0 < DDEC; c0 += 128) {
    f32x4 dacc[4][4] = {};
    mma_tile_l(Hs + wm * 64 * 136, Wd1b + (size_t)(c0 + wn * 64) * D, D, dacc, lane);
    __syncthreads();  // previous chunk's Dn reads complete before overwrite
#pragma unroll
    for (int n = 0; n < 4; ++n) {
      int lc = wn * 64 + n * 16 + cr;
      int c = c0 + lc;
      float bb = bd1[c], sc = scale[c], sh = shift[c];
#pragma unroll
      for (int m = 0; m < 4; ++m)
#pragma unroll
        for (int rr = 0; rr < 4; ++rr) {
          float v = dacc[m][n][rr] + bb;
          v = v * sc + sh;
          v = (v >= 0.f) ? v : 0.01f * v;
          Dn[(wm * 64 + m * 16 + g * 4 + rr) * 136 + lc] = f2bf(v);
        }
    }
    __syncthreads();
    mma_tile_l(Dn + wm * 64 * 136, Wd2b + (size_t)(wn * 64) * DDEC + c0, DDEC, acc, lane);
  }
#pragma unroll
  for (int n = 0; n < 4; ++n) {
    int col = wn * 64 + n * 16 + cr;
    float b = bd2[col];
#pragma unroll
    for (int m = 0; m < 4; ++m)
#pragma unroll
      for (int rr = 0; rr < 4; ++rr) {
        int row = row0 + wm * 64 + m * 16 + g * 4 + rr;
        if (row < N) rec[(size_t)row * D + col] = acc[m][n][rr] + b;
      }
  }
}

// ------------------------------------------------- z = prelu(h@Wp^T + bp, a)
__global__ __launch_bounds__(256, 2) void gemm_z_mfma(
    const float* __restrict__ h, const ushort* __restrict__ Wpb,
    const float* __restrict__ bp, const float* __restrict__ ap,
    float* __restrict__ z, int N)
{
  __shared__ ushort As[128 * 136];
  const int t = threadIdx.x;
  const int row0 = blockIdx.x * 128;
  stage128(h, N, row0, As, t);
  __syncthreads();
  const int lane = t & 63, w = t >> 6;
  const int wm = w >> 1, wn = w & 1;
  f32x4 acc[4][4] = {};
  mma_tile_l(As + wm * 64 * 136, Wpb + (size_t)(wn * 64) * D, D, acc, lane);
  const float alpha = ap[0];
  const int g = lane >> 4, cr = lane & 15;
#pragma unroll
  for (int n = 0; n < 4; ++n) {
    int col = wn * 64 + n * 16 + cr;
    float b = bp[col];
#pragma unroll
    for (int m = 0; m < 4; ++m)
#pragma unroll
      for (int rr = 0; rr < 4; ++rr) {
        int row = row0 + wm * 64 + m * 16 + g * 4 + rr;
        if (row < N) {
          float v = acc[m][n][rr] + b;
          z[(size_t)row * D + col] = (v >= 0.f) ? v : alpha * v;
        }
      }
  }
}

// ---------------------------------------------------------------- launch
extern "C" void kernel_launch(void* const* d_in, const int* in_sizes, int n_in,
                              void* d_out, int out_size, void* d_ws, size_t ws_size,
                              hipStream_t stream)
{
  const float* x   = (const float*)d_in[0];
  const int*   ei  = (const int*)d_in[1];
  const float* Wl  = (const float*)d_in[2];
  const float* bl  = (const float*)d_in[3];
  const float* Wr  = (const float*)d_in[4];
  const float* Wp  = (const float*)d_in[5];
  const float* bp  = (const float*)d_in[6];
  const float* ap  = (const float*)d_in[7];
  const float* Wd1 = (const float*)d_in[8];
  const float* bd1 = (const float*)d_in[9];
  const float* gm  = (const float*)d_in[10];
  const float* bt  = (const float*)d_in[11];
  const float* Wd2 = (const float*)d_in[12];
  const float* bd2 = (const float*)d_in[13];

  const int N = in_sizes[0] / D;   // 100000
  const int E = in_sizes[1] / 2;   // 1600000

  float* h_out   = (float*)d_out;
  float* z_out   = h_out + (size_t)N * D;
  float* rec_out = z_out + (size_t)N * D;
  float* tgt_out = rec_out + (size_t)N * D;

  // small scratch in ws (~9KB)
  float* sums  = (float*)d_ws;
  float* sumsq = sums + DDEC;
  float* scale = sumsq + DDEC;
  float* shift = scale + DDEC;
  int*   flag  = (int*)(shift + DDEC);
  int*   bsum  = flag + 1;  // 256 ints

  // big scratch in the tgt output slot (51.2 MB, written last):
  int* colidx = (int*)tgt_out;                      // E ints (6.4 MB)
  int* deg    = colidx + E;                         // N ints
  int* fillc  = deg + N;                            // N ints
  int* rowptr = fillc + N;                          // N+1 ints (ends ~7.6 MB)
  ushort* xb  = (ushort*)(tgt_out + 2000000);       // byte 8 MB, 25.6 MB
  ushort* wb  = (ushort*)(tgt_out + 8500000);       // byte 34 MB, 360 KB
  ushort* Wlb  = wb;
  ushort* Wrb  = wb + 16384;
  ushort* Wpb  = wb + 32768;
  ushort* Wd1b = wb + 49152;
  ushort* Wd2b = wb + 114688;

  // z slot scratch (dead before gemm_z runs):
  ushort* aggrb = (ushort*)z_out;                   // 25.6 MB
  ushort* hb    = aggrb + (size_t)N * D;            // 25.6 MB (ends exactly at z slot end)

  hipMemsetAsync(deg, 0, (size_t)2 * N * sizeof(int), stream);  // deg + fillc
  hipMemsetAsync(sums, 0, (size_t)2 * DDEC * sizeof(float), stream);

  detect_i64<<<1, 64, 0, stream>>>(ei, flag);
  wcvt_kernel<<<704, 256, 0, stream>>>(Wl, Wr, Wp, Wd1, Wd2, wb);

  int n8 = N * 16;  // groups of 8 floats
  xcvt_kernel<<<(n8 + 255) / 256, 256, 0, stream>>>(x, xb, n8);

  int eb = (E + 255) / 256;
  count_deg<<<eb, 256, 0, stream>>>(ei, deg, flag, E);

  int NB = (N + 1023) / 1024;
  scan_reduce<<<NB, 256, 0, stream>>>(deg, bsum, N);
  scan_bsum<<<1, 256, 0, stream>>>(bsum, rowptr, NB, N, E);
  scan_final<<<NB, 256, 0, stream>>>(deg, bsum, rowptr, N);

  fill_csr<<<eb, 256, 0, stream>>>(ei, rowptr, fillc, colidx, flag, E);

  long long ag_threads = (long long)N * 64;
  aggregate_kernel<<<(int)((ag_threads + 255) / 256), 256, 0, stream>>>(
      rowptr, colidx, xb, aggrb, N);

  int rb = (N + 127) / 128;
  gemm_h_mfma<<<rb, 256, 0, stream>>>(aggrb, xb, Wlb, Wrb, bl, h_out, hb, N);

  dstat_mfma<<<rb, 256, 0, stream>>>(hb, Wd1b, bd1, sums, sumsq, N);
  finalize_kernel<<<2, 256, 0, stream>>>(sums, sumsq, gm, bt, scale, shift, N);

  rec_mfma<<<rb, 256, 0, stream>>>(hb, Wd1b, Wd2b, bd1, scale, shift, bd2, rec_out, N);

  gemm_z_mfma<<<rb, 256, 0, stream>>>(h_out, Wpb, bp, ap, z_out, N);

  hipMemcpyAsync(tgt_out, x, (size_t)N * D * sizeof(float), hipMemcpyDeviceToDevice, stream);
}